// Round 8
// baseline (613.680 us; speedup 1.0000x reference)
//
#include <hip/hip_runtime.h>
#include <stdint.h>

// ---------------------------------------------------------------------------
// GAU forward on MI355X (gfx950), bf16 MFMA everywhere.
//   hid|qk = silu(x@[Wh|Wqk]+b) -> vT [2048][8192], gate [8192][2048],
//                                  q,k bf16 [8192][256] (cols 200..255 zero)
//   attn = relu(q@kT / 32)^2    bf16 (full [8192][8192] if ws allows)
//   out2 = (attn@v) * gate      bf16 [8192][2048]
//   y    = (out2@Wo + bo) * x   fp32 [8192][1024]
//
// R15: k_pv -> BK=64 ring-2 (was BK=32 ring-4). R14 showed reg-dbuf is null
// (228 vs 222 us) -> per-tile cost is sync ramp and/or LDS throughput, not
// read placement. BK=64 halves barriers/vmcnt per K (diagnostic: fixed
// per-barrier cost halves; throughput cost stays). One vmcnt(0)+barrier per
// 64-K tile; stage loads get the full ~2900-cyc tile of flight so the drain
// is free. 8-octet swizzle: phys_oct = logical ^ (row&7), both-sides
// (inverse-swizzled global source + swizzled read offset), conflict-free.
// Reg-dbuf removed (measured null). k_hidqk / k_attn / k_final unchanged
// from R14 to isolate the variable.
// ---------------------------------------------------------------------------

typedef __bf16 bf16x8 __attribute__((ext_vector_type(8)));
typedef float f32x4 __attribute__((ext_vector_type(4)));

__device__ __forceinline__ uint16_t f2bf(float f) {
  uint32_t u = __builtin_bit_cast(uint32_t, f);
  u += 0x7fffu + ((u >> 16) & 1u);   // RNE; inputs are finite
  return (uint16_t)(u >> 16);
}
__device__ __forceinline__ float silu_f(float s) {
  return s / (1.f + __expf(-s));
}

__device__ __forceinline__ void gload16(const void* g, void* l) {
  __builtin_amdgcn_global_load_lds(
      (__attribute__((address_space(1))) void*)const_cast<void*>(g),
      (__attribute__((address_space(3))) void*)l, 16, 0, 0);
}

// ---------------- elementwise prep ----------------

__global__ void cast_to_bf16(const float* __restrict__ in, uint16_t* __restrict__ out, int n4) {
  int i = blockIdx.x * blockDim.x + threadIdx.x;
  if (i < n4) {
    float4 f = ((const float4*)in)[i];
    ushort4 o;
    o.x = f2bf(f.x); o.y = f2bf(f.y); o.z = f2bf(f.z); o.w = f2bf(f.w);
    ((ushort4*)out)[i] = o;
  }
}

// out[c][r] = (c < C) ? (bf16)in[r][c] : 0   ; out is [Cp][R]
__global__ void transpose_cast_pad(const float* __restrict__ in, uint16_t* __restrict__ out,
                                   int R, int C, int Cp) {
  __shared__ float tile[32][33];
  int cb = blockIdx.x * 32;
  int rb = blockIdx.y * 32;
  int tx = threadIdx.x;
  int ty = threadIdx.y;
#pragma unroll
  for (int i = 0; i < 4; ++i) {
    int r = rb + ty + i * 8;
    int c = cb + tx;
    tile[ty + i * 8][tx] = (c < C) ? in[(size_t)r * C + c] : 0.f;
  }
  __syncthreads();
#pragma unroll
  for (int i = 0; i < 4; ++i) {
    int c = cb + ty + i * 8;
    if (c < Cp) out[(size_t)c * R + rb + tx] = f2bf(tile[tx][ty + i * 8]);
  }
}

// k_sum: P0 = (P0 + P1) * gate, elementwise bf16x8, in-place (striped path).
__global__ void k_sum(uint16_t* __restrict__ P0, const uint16_t* __restrict__ P1,
                      const uint16_t* __restrict__ g, int n8) {
  int i = blockIdx.x * blockDim.x + threadIdx.x;
  if (i < n8) {
    bf16x8 a = ((const bf16x8*)P0)[i];
    bf16x8 b = ((const bf16x8*)P1)[i];
    bf16x8 gg = ((const bf16x8*)g)[i];
    bf16x8 o;
#pragma unroll
    for (int e = 0; e < 8; ++e)
      o[e] = (__bf16)(((float)a[e] + (float)b[e]) * (float)gg[e]);
    ((bf16x8*)P0)[i] = o;
  }
}

// ---------------- params ----------------

struct EpiParams {
  const float* bias;
  const float* bias2;
  const float* g0;
  const float* b0;
  const float* g1;
  const float* b1;
  const uint16_t* gate;
  const float* x;
  uint16_t* o16a;
  uint16_t* o16b;
  uint16_t* oq;
  uint16_t* ok;
  float* o32;
};

// ---------------------------------------------------------------------------
// 256x256 8-wave reg-dbuf engine (k_hidqk / k_attn; unchanged from R14).
// ---------------------------------------------------------------------------
#define ET(T_, WS_, RS_, CA_, CB_, NA_, NB_)                                   \
  do {                                                                         \
    const int kp_ = (((T_) + 3) & (NT - 1)) * 32;                              \
    uint16_t* sd_ = SH + (WS_) * 16384 + wave * 512;                           \
    gload16(gA0 + kp_, sd_);                                                   \
    gload16(gA1 + kp_, sd_ + 4096);                                            \
    gload16(gB0 + kp_, sd_ + 8192);                                            \
    gload16(gB1 + kp_, sd_ + 12288);                                           \
    const uint16_t* rb_ = SH + (RS_) * 16384;                                  \
    _Pragma("unroll") for (int j_ = 0; j_ < 4; ++j_)                           \
        NB_[j_] = *(const bf16x8*)(rb_ + rdB + j_ * 512);                      \
    _Pragma("unroll") for (int i_ = 0; i_ < 8; ++i_)                           \
        NA_[i_] = *(const bf16x8*)(rb_ + rdA + i_ * 512);                      \
    __builtin_amdgcn_sched_barrier(0);                                         \
    __builtin_amdgcn_s_setprio(1);                                             \
    _Pragma("unroll") for (int i_ = 0; i_ < 8; ++i_)                           \
      _Pragma("unroll") for (int j_ = 0; j_ < 4; ++j_)                         \
          acc[i_][j_] = __builtin_amdgcn_mfma_f32_16x16x32_bf16(               \
              CA_[i_], CB_[j_], acc[i_][j_], 0, 0, 0);                         \
    __builtin_amdgcn_s_setprio(0);                                             \
    asm volatile("s_waitcnt vmcnt(4)" ::: "memory");                           \
    __builtin_amdgcn_sched_barrier(0);                                         \
    __builtin_amdgcn_s_barrier();                                              \
    __builtin_amdgcn_sched_barrier(0);                                         \
  } while (0)

#define ENGINE256()                                                            \
  do {                                                                         \
    _Pragma("unroll") for (int s_ = 0; s_ < 3; ++s_) {                         \
      uint16_t* d_ = SH + s_ * 16384 + wave * 512;                             \
      gload16(gA0 + s_ * 32, d_);                                              \
      gload16(gA1 + s_ * 32, d_ + 4096);                                       \
      gload16(gB0 + s_ * 32, d_ + 8192);                                       \
      gload16(gB1 + s_ * 32, d_ + 12288);                                      \
    }                                                                          \
    asm volatile("s_waitcnt vmcnt(4)" ::: "memory");                           \
    __builtin_amdgcn_sched_barrier(0);                                         \
    __builtin_amdgcn_s_barrier();                                              \
    __builtin_amdgcn_sched_barrier(0);                                         \
    _Pragma("unroll") for (int j_ = 0; j_ < 4; ++j_)                           \
        fb0[j_] = *(const bf16x8*)(SH + rdB + j_ * 512);                       \
    _Pragma("unroll") for (int i_ = 0; i_ < 8; ++i_)                           \
        fa0[i_] = *(const bf16x8*)(SH + rdA + i_ * 512);                       \
    for (int t0_ = 0; t0_ < NT; t0_ += 4) {                                    \
      ET(t0_ + 0, 3, 1, fa0, fb0, fa1, fb1);                                   \
      ET(t0_ + 1, 0, 2, fa1, fb1, fa0, fb0);                                   \
      ET(t0_ + 2, 1, 3, fa0, fb0, fa1, fb1);                                   \
      ET(t0_ + 3, 2, 0, fa1, fb1, fa0, fb0);                                   \
    }                                                                          \
    asm volatile("s_waitcnt vmcnt(0)" ::: "memory");                           \
    __builtin_amdgcn_sched_barrier(0);                                         \
    __syncthreads();                                                           \
  } while (0)

// 128x128 4-wave ring-4 engine (k_final only).
#define TILE128(T_, B_, BS_)                                                   \
  do {                                                                         \
    const uint16_t* base_ = SH + (B_) * 8192;                                  \
    const int kp_ = (((T_) + 3) & (NT - 1)) * 32;                              \
    uint16_t* sd_ = SH + (BS_) * 8192 + wave * 512;                            \
    gload16(gA0 + kp_, sd_);                                                   \
    gload16(gA1 + kp_, sd_ + 2048);                                            \
    gload16(gB0 + kp_, sd_ + 4096);                                            \
    gload16(gB1 + kp_, sd_ + 6144);                                            \
    bf16x8 a_[4], b_[4];                                                       \
    _Pragma("unroll") for (int j_ = 0; j_ < 4; ++j_)                           \
        b_[j_] = *(const bf16x8*)(base_ + rdB + j_ * 512);                     \
    _Pragma("unroll") for (int i_ = 0; i_ < 4; ++i_)                           \
        a_[i_] = *(const bf16x8*)(base_ + rdA + i_ * 512);                     \
    __builtin_amdgcn_s_setprio(1);                                             \
    _Pragma("unroll") for (int i_ = 0; i_ < 4; ++i_)                           \
      _Pragma("unroll") for (int j_ = 0; j_ < 4; ++j_)                         \
          acc[i_][j_] = __builtin_amdgcn_mfma_f32_16x16x32_bf16(               \
              a_[i_], b_[j_], acc[i_][j_], 0, 0, 0);                           \
    __builtin_amdgcn_s_setprio(0);                                             \
    asm volatile("s_waitcnt vmcnt(8)" ::: "memory");                           \
    __builtin_amdgcn_sched_barrier(0);                                         \
    __builtin_amdgcn_s_barrier();                                              \
    __builtin_amdgcn_sched_barrier(0);                                         \
  } while (0)

#define RING_LOOP128()                                                         \
  do {                                                                         \
    _Pragma("unroll") for (int s_ = 0; s_ < 3; ++s_) {                         \
      uint16_t* d_ = SH + s_ * 8192 + wave * 512;                              \
      gload16(gA0 + s_ * 32, d_);                                              \
      gload16(gA1 + s_ * 32, d_ + 2048);                                       \
      gload16(gB0 + s_ * 32, d_ + 4096);                                       \
      gload16(gB1 + s_ * 32, d_ + 6144);                                       \
    }                                                                          \
    asm volatile("s_waitcnt vmcnt(8)" ::: "memory");                           \
    __builtin_amdgcn_sched_barrier(0);                                         \
    __builtin_amdgcn_s_barrier();                                              \
    __builtin_amdgcn_sched_barrier(0);                                         \
    for (int t0_ = 0; t0_ < NT; t0_ += 4) {                                    \
      TILE128(t0_ + 0, 0, 3);                                                  \
      TILE128(t0_ + 1, 1, 0);                                                  \
      TILE128(t0_ + 2, 2, 1);                                                  \
      TILE128(t0_ + 3, 3, 2);                                                  \
    }                                                                          \
    asm volatile("s_waitcnt vmcnt(0)" ::: "memory");                           \
    __builtin_amdgcn_sched_barrier(0);                                         \
    __syncthreads();                                                           \
  } while (0)

// ---------------------------------------------------------------------------
// k_hidqk: C = xb[8192,1024] @ [WhT;WqkT][4352,1024]^T, 256x256, 8 waves.
// ---------------------------------------------------------------------------
__global__ __launch_bounds__(512, 2) void k_hidqk(
    const uint16_t* __restrict__ A, const uint16_t* __restrict__ Bt, EpiParams p) {
  __shared__ __align__(16) uint16_t SH[65536];   // 128 KB ring

  const int tid = threadIdx.x;
  const int lane = tid & 63;
  const int wave = tid >> 6;
  const int wrM = (wave >> 2) * 128;
  const int wcN = (wave & 3) * 64;
  const int m0 = blockIdx.y * 256;
  const int n0 = blockIdx.x * 256;
  const int lda = 1024, ldb = 1024;
  const int NT = 32;   // K=1024

  f32x4 acc[8][4] = {};

  const int fr = lane & 15;
  const int rg = lane >> 4;
  const int swz = (rg ^ ((fr >> 1) & 3)) * 8;
  const int rdA = (wrM + fr) * 32 + swz;
  const int rdB = 8192 + (wcN + fr) * 32 + swz;

  const int srow = lane >> 2;
  const int sk = ((lane & 3) ^ ((lane >> 3) & 3)) * 8;
  const uint16_t* gA0 = A + (size_t)(m0 + wave * 16 + srow) * lda + sk;
  const uint16_t* gA1 = gA0 + (size_t)128 * lda;
  const uint16_t* gB0 = Bt + (size_t)(n0 + wave * 16 + srow) * ldb + sk;
  const uint16_t* gB1 = gB0 + (size_t)128 * ldb;

  bf16x8 fa0[8], fb0[4], fa1[8], fb1[4];
  ENGINE256();

  // C/D layout: col = lane&15, row = rg*4 + reg   [m89-verified]
  if (n0 < 2048) {
    // vT transposed store. Per j: arena [16 n][128 m + 8 pad] stride 136.
    uint16_t* ar = SH + wave * 2304;
#pragma unroll
    for (int j = 0; j < 4; ++j) {
      const float bc = p.bias[n0 + wcN + j * 16 + fr];
#pragma unroll
      for (int i = 0; i < 8; ++i)
#pragma unroll
        for (int r = 0; r < 4; ++r)
          ar[fr * 136 + i * 16 + rg * 4 + r] = f2bf(silu_f(acc[i][j][r] + bc));
      const int mc = (lane & 15) * 8;
#pragma unroll
      for (int it = 0; it < 4; ++it) {
        const int nrow = it * 4 + (lane >> 4);
        bf16x8 v = *(const bf16x8*)(ar + nrow * 136 + mc);
        *(bf16x8*)(p.o16a + (size_t)(n0 + wcN + j * 16 + nrow) * 8192 + m0 + wrM + mc) = v;
      }
    }
  } else if (n0 < 4096) {
    // gate. Per i: arena [16 m][64 n + pad] stride 72.
    uint16_t* ar = SH + wave * 2048;
    const int lrow = lane >> 3;
    const int nc = (lane & 7) * 8;
    float bc[4];
#pragma unroll
    for (int j = 0; j < 4; ++j) bc[j] = p.bias[n0 + wcN + j * 16 + fr];
#pragma unroll
    for (int i = 0; i < 8; ++i) {
#pragma unroll
      for (int j = 0; j < 4; ++j)
#pragma unroll
        for (int r = 0; r < 4; ++r)
          ar[(rg * 4 + r) * 72 + j * 16 + fr] = f2bf(silu_f(acc[i][j][r] + bc[j]));
#pragma unroll
      for (int rr = 0; rr < 2; ++rr) {
        bf16x8 v = *(const bf16x8*)(ar + (rr * 8 + lrow) * 72 + nc);
        *(bf16x8*)(p.o16b + (size_t)(m0 + wrM + i * 16 + rr * 8 + lrow) * 2048 + (n0 - 2048) + wcN + nc) = v;
      }
    }
  } else {
    // q,k: stride 256, cols 200..255 forced zero. n0==4096 -> qc = wcN+j*16+fr.
#pragma unroll
    for (int i = 0; i < 8; ++i) {
#pragma unroll
      for (int j = 0; j < 4; ++j) {
        const int row = m0 + wrM + i * 16 + rg * 4;
        const int qc = wcN + j * 16 + fr;   // 0..255
#pragma unroll
        for (int r = 0; r < 4; ++r) {
          float qv = 0.f, kv = 0.f;
          if (qc < 200) {
            float s = silu_f(acc[i][j][r] + p.bias2[qc]);
            qv = s * p.g0[qc] + p.b0[qc];
            kv = s * p.g1[qc] + p.b1[qc];
          }
          p.oq[(size_t)(row + r) * 256 + qc] = f2bf(qv);
          p.ok[(size_t)(row + r) * 256 + qc] = f2bf(kv);
        }
      }
    }
  }
}

// ---------------------------------------------------------------------------
// k_attn: attn = relu(q@kT/32)^2, K=256 (padded), 256x256 tile, 8 waves.
// ---------------------------------------------------------------------------
__global__ __launch_bounds__(512, 2) void k_attn(
    const uint16_t* __restrict__ Q,
    const uint16_t* __restrict__ Kt,
    uint16_t* __restrict__ attn) {
  __shared__ __align__(16) uint16_t SH[65536];

  const int tid = threadIdx.x;
  const int lane = tid & 63;
  const int wave = tid >> 6;
  const int wrM = (wave >> 2) * 128;
  const int wcN = (wave & 3) * 64;
  const int m0 = blockIdx.y * 256;
  const int n0 = blockIdx.x * 256;
  const int lda = 256, ldb = 256;
  const int NT = 8;   // K=256

  f32x4 acc[8][4] = {};

  const int fr = lane & 15;
  const int rg = lane >> 4;
  const int swz = (rg ^ ((fr >> 1) & 3)) * 8;
  const int rdA = (wrM + fr) * 32 + swz;
  const int rdB = 8192 + (wcN + fr) * 32 + swz;

  const int srow = lane >> 2;
  const int sk = ((lane & 3) ^ ((lane >> 3) & 3)) * 8;
  const uint16_t* gA0 = Q + (size_t)(m0 + wave * 16 + srow) * lda + sk;
  const uint16_t* gA1 = gA0 + (size_t)128 * lda;
  const uint16_t* gB0 = Kt + (size_t)(n0 + wave * 16 + srow) * ldb + sk;
  const uint16_t* gB1 = gB0 + (size_t)128 * ldb;

  bf16x8 fa0[8], fb0[4], fa1[8], fb1[4];
  ENGINE256();

  uint16_t* ar = SH + wave * 2048;
  const int row = lane >> 2;
  const int c0 = (lane & 3) * 16;
#pragma unroll
  for (int i = 0; i < 8; ++i) {
#pragma unroll
    for (int j = 0; j < 4; ++j)
#pragma unroll
      for (int r = 0; r < 4; ++r) {
        float s = fmaxf(acc[i][j][r] * 0.03125f, 0.f);
        ar[(rg * 4 + r) * 72 + j * 16 + fr] = f2bf(s * s);
      }
    bf16x8 v0 = *(const bf16x8*)(ar + row * 72 + c0);
    bf16x8 v1 = *(const bf16x8*)(ar + row * 72 + c0 + 8);
    uint16_t* dst = attn + (size_t)(m0 + wrM + i * 16 + row) * 8192 + (n0 + wcN + c0);
    *(bf16x8*)(dst) = v0;
    *(bf16x8*)(dst + 8) = v1;
  }
}

// ---------------------------------------------------------------------------
// k_pv: out2 = (attn@v)[*gate]. 256x256 tile, 8 waves, BK=64 ring-2.
// Slot s (64 KB): A[256][64] at s*32768, B[256][64] at +16384 (uint16).
// 8-oct swizzle: LDS phys octet p of row r holds logical octet p^(r&7);
// read logical (kk*4+rg) at phys ((kk*4+rg)^(fr&7)). Stage: wave w rows
// [w*32,+32), 4 gloads A + 4 B; source pre-inverse-swizzled. One
// vmcnt(0)+barrier per 64-K tile (stage has full-tile flight).
// split=0 (fullM): K=8192 (NT=128); split=1: K=4096 (NT=64) kv-halves.
// ---------------------------------------------------------------------------
__global__ __launch_bounds__(512, 2) void k_pv(
    const uint16_t* __restrict__ A,
    const uint16_t* __restrict__ Bt,
    uint16_t* __restrict__ P0,
    uint16_t* __restrict__ P1,
    const uint16_t* __restrict__ gate,
    int split) {
  __shared__ __align__(16) uint16_t SH[65536];   // 2 x 64 KB slots

  const int id = blockIdx.x;
  int bx, by, kv0, NT;
  uint16_t* dst;
  if (split) {
    bx = id & 7;
    by = id >> 4;
    kv0 = ((id >> 3) & 1) * 4096;
    NT = 64;
    dst = ((id >> 3) & 1) ? P1 : P0;
  } else {
    bx = (id >> 3) & 7;
    by = (id & 7) + 8 * (id >> 6);
    kv0 = 0;
    NT = 128;
    dst = P0;
  }
  const int m0 = by * 256;
  const int n0 = bx * 256;

  const int tid = threadIdx.x;
  const int lane = tid & 63;
  const int wave = tid >> 6;
  const int wrM = (wave >> 2) * 128;
  const int wcN = (wave & 3) * 64;

  const int fr = lane & 15;
  const int rg = lane >> 4;
  const int fr7 = fr & 7;
  // read element offsets: + i*1024 (A) / j*1024 (B), per kk half
  const int octr0 = ((0 * 4 + rg) ^ fr7) * 8;
  const int octr1 = ((1 * 4 + rg) ^ fr7) * 8;
  const int rdA0 = (wrM + fr) * 64;
  const int rdB0 = 16384 + (wcN + fr) * 64;

  // stage: lane covers row chunk lane>>3, phys octet lane&7 -> fetch
  // logical octet (lane&7)^(lane>>3) from global.
  const int srow8 = lane >> 3;
  const int soct = ((lane & 7) ^ srow8) * 8;
  const uint16_t* gA = A + (size_t)(m0 + wave * 32 + srow8) * 8192 + kv0 + soct;
  const uint16_t* gB = Bt + (size_t)(n0 + wave * 32 + srow8) * 8192 + kv0 + soct;

  f32x4 acc[8][4] = {};

  // prologue: stage slot 0 = tile 0
#pragma unroll
  for (int g = 0; g < 4; ++g) {
    gload16(gA + (size_t)(g * 8) * 8192, SH + (wave * 32 + g * 8) * 64);
    gload16(gB + (size_t)(g * 8) * 8192, SH + 16384 + (wave * 32 + g * 8) * 64);
  }
  asm volatile("s_waitcnt vmcnt(0)" ::: "memory");
  __builtin_amdgcn_sched_barrier(0);
  __builtin_amdgcn_s_barrier();
  __builtin_amdgcn_sched_barrier(0);

  for (int t = 0; t < NT; ++t) {
    const int cur = t & 1;
    // stage tile t+1 (wrapped on last iter; dead data, drained in-loop)
    const int kn = ((t + 1) & (NT - 1)) * 64;
    uint16_t* sd = SH + (cur ^ 1) * 32768;
#pragma unroll
    for (int g = 0; g < 4; ++g) {
      gload16(gA + kn + (size_t)(g * 8) * 8192, sd + (wave * 32 + g * 8) * 64);
      gload16(gB + kn + (size_t)(g * 8) * 8192, sd + 16384 + (wave * 32 + g * 8) * 64);
    }
    const uint16_t* sb = SH + cur * 32768;
    // kk = 0
    {
      bf16x8 aq[8], bq[4];
#pragma unroll
      for (int j = 0; j < 4; ++j)
        bq[j] = *(const bf16x8*)(sb + rdB0 + j * 1024 + octr0);
#pragma unroll
      for (int i = 0; i < 8; ++i)
        aq[i] = *(const bf16x8*)(sb + rdA0 + i * 1024 + octr0);
      __builtin_amdgcn_s_setprio(1);
#pragma unroll
      for (int i = 0; i < 8; ++i)
#pragma unroll
        for (int j = 0; j < 4; ++j)
          acc[i][j] = __builtin_amdgcn_mfma_f32_16x16x32_bf16(
              aq[i], bq[j], acc[i][j], 0, 0, 0);
      __builtin_amdgcn_s_setprio(0);
    }
    // kk = 1
    {
      bf16x8 aq[8], bq[4];
#pragma unroll
      for (int j = 0; j < 4; ++j)
        bq[j] = *(const bf16x8*)(sb + rdB0 + j * 1024 + octr1);
#pragma unroll
      for (int i = 0; i < 8; ++i)
        aq[i] = *(const bf16x8*)(sb + rdA0 + i * 1024 + octr1);
      __builtin_amdgcn_s_setprio(1);
#pragma unroll
      for (int i = 0; i < 8; ++i)
#pragma unroll
        for (int j = 0; j < 4; ++j)
          acc[i][j] = __builtin_amdgcn_mfma_f32_16x16x32_bf16(
              aq[i], bq[j], acc[i][j], 0, 0, 0);
      __builtin_amdgcn_s_setprio(0);
    }
    asm volatile("s_waitcnt vmcnt(0)" ::: "memory");
    __builtin_amdgcn_sched_barrier(0);
    __builtin_amdgcn_s_barrier();
    __builtin_amdgcn_sched_barrier(0);
  }

  // epilogue: per-wave [16][72] arena bounce, 16B stores (gated if fullM)
  uint16_t* ar = SH + wave * 2048;
  const int lrow = lane >> 3;
  const int nc = (lane & 7) * 8;
#pragma unroll
  for (int i = 0; i < 8; ++i) {
#pragma unroll
    for (int j = 0; j < 4; ++j)
#pragma unroll
      for (int r = 0; r < 4; ++r)
        ar[(rg * 4 + r) * 72 + j * 16 + fr] = f2bf(acc[i][j][r]);
#pragma unroll
    for (int rr = 0; rr < 2; ++rr) {
      const size_t base = (size_t)(m0 + wrM + i * 16 + rr * 8 + lrow) * 2048 + n0 + wcN + nc;
      bf16x8 v = *(const bf16x8*)(ar + (rr * 8 + lrow) * 72 + nc);
      if (gate) {
        bf16x8 g = *(const bf16x8*)(gate + base);
        bf16x8 o;
#pragma unroll
        for (int e = 0; e < 8; ++e) o[e] = (__bf16)((float)v[e] * (float)g[e]);
        *(bf16x8*)(dst + base) = o;
      } else {
        *(bf16x8*)(dst + base) = v;
      }
    }
  }
}

// ---------------------------------------------------------------------------
// k_final: y = (out2g@WoT^T + bo) * x, fp32 out. 128x128, K=2048, ring-4.
// ---------------------------------------------------------------------------
__global__ __launch_bounds__(256, 2) void k_final(
    const uint16_t* __restrict__ A,
    const uint16_t* __restrict__ Bt, EpiParams p) {
  __shared__ __align__(16) uint16_t SH[32768];

  const int tid = threadIdx.x;
  const int lane = tid & 63;
  const int wave = tid >> 6;
  const int wr = (wave >> 1) * 64;
  const int wc = (wave & 1) * 64;
  const int m0 = blockIdx.y * 128;
  const int n0 = blockIdx.x * 128;
  const int lda = 2048, ldb = 2048;
  const int NT = 64;   // K=2048

  f32x4 acc[4][4] = {};

  const int fr = lane & 15;
  const int rg = lane >> 4;
  const int swz = (rg ^ ((fr >> 1) & 3)) * 8;
  const int rdA = (wr + fr) * 32 + swz;
  const int rdB = 4096 + (wc + fr) * 32 + swz;

  const int srow = lane >> 2;
  const int sk = ((lane & 3) ^ ((lane >> 3) & 3)) * 8;
  const uint16_t* gA0 = A + (size_t)(m0 + wave * 16 + srow) * lda + sk;
  const uint16_t* gA1 = gA0 + (size_t)64 * lda;
  const uint16_t* gB0 = Bt + (size_t)(n0 + wave * 16 + srow) * ldb + sk;
  const uint16_t* gB1 = gB0 + (size_t)64 * ldb;

  RING_LOOP128();

#pragma unroll
  for (int i = 0; i < 4; ++i) {
#pragma unroll
    for (int j = 0; j < 4; ++j) {
      const int row = m0 + wr + i * 16 + rg * 4;
      const int col = n0 + wc + j * 16 + fr;
      const float bc = p.bias[col];
#pragma unroll
      for (int r = 0; r < 4; ++r) {
        size_t idx = (size_t)(row + r) * 1024 + col;
        p.o32[idx] = (acc[i][j][r] + bc) * p.x[idx];
      }
    }
  }
}

// ---------------- launch ----------------

extern "C" void kernel_launch(void* const* d_in, const int* in_sizes, int n_in,
                              void* d_out, int out_size, void* d_ws, size_t ws_size,
                              hipStream_t stream) {
  const float* x        = (const float*)d_in[0];
  const float* W_hidden = (const float*)d_in[1];
  const float* b_hidden = (const float*)d_in[2];
  const float* W_qk     = (const float*)d_in[3];
  const float* b_qk     = (const float*)d_in[4];
  const float* gamma    = (const float*)d_in[5];
  const float* beta     = (const float*)d_in[6];
  const float* W_out    = (const float*)d_in[7];
  const float* b_out    = (const float*)d_in[8];
  float* out = (float*)d_out;

  const bool fullM = ws_size >= (236ull << 20);
  const size_t region0 = fullM ? (128ull << 20) : (64ull << 20);

  char* base = (char*)d_ws;
  uint16_t* xb    = (uint16_t*)(base);                         // 16 MB  [8192][1024]
  uint16_t* WhT   = (uint16_t*)(base + (16ull << 20));         //  8 MB  [4096][1024]
  uint16_t* WqkT  = (uint16_t*)(base + (24ull << 20));         // .5 MB  [256][1024]
  uint16_t* attnB = (uint16_t*)(base);                         // 64/128 MB
  char* tail = base + region0;
  uint16_t* WoT   = (uint16_t*)(tail);                         //  4 MB  [1024][2048]
  uint16_t* q     = (uint16_t*)(tail + (4ull << 20));          //  4 MB  [8192][256]
  uint16_t* kk    = (uint16_t*)(tail + (8ull << 20));          //  4 MB
  uint16_t* vT    = (uint16_t*)(tail + (12ull << 20));         // 32 MB  [2048][8192]
  uint16_t* gate  = (uint16_t*)(tail + (44ull << 20));         // 32 MB  [8192][2048]
  uint16_t* out2g = (uint16_t*)(tail + (76ull << 20));         // 32 MB  [8192][2048]
  (void)in_sizes; (void)n_in; (void)out_size;

  // prep
  cast_to_bf16<<<(8192 * 1024 / 4) / 256, 256, 0, stream>>>(x, xb, 8192 * 1024 / 4);
  transpose_cast_pad<<<dim3(4096 / 32, 1024 / 32), dim3(32, 8), 0, stream>>>(W_hidden, WhT, 1024, 4096, 4096);
  transpose_cast_pad<<<dim3(256 / 32, 1024 / 32), dim3(32, 8), 0, stream>>>(W_qk, WqkT, 1024, 200, 256);
  transpose_cast_pad<<<dim3(1024 / 32, 2048 / 32), dim3(32, 8), 0, stream>>>(W_out, WoT, 2048, 1024, 1024);

  // fused hid + qk   (N = 4096 + 256 = 4352; blocks x: 0..7 vT, 8..15 gate, 16 qk)
  {
    EpiParams p{};
    p.bias = b_hidden; p.bias2 = b_qk;
    p.g0 = gamma; p.b0 = beta; p.g1 = gamma + 200; p.b1 = beta + 200;
    p.o16a = vT; p.o16b = gate; p.oq = q; p.ok = kk;
    k_hidqk<<<dim3(17, 32), 512, 0, stream>>>(xb, WhT, p);
  }

  if (fullM) {
    k_attn<<<dim3(32, 32), 512, 0, stream>>>(q, kk, attnB);
    k_pv<<<dim3(256), 512, 0, stream>>>(attnB, vT, out2g, nullptr, gate, 0);
    EpiParams p{};
    p.bias = b_out; p.x = x; p.o32 = out;
    k_final<<<dim3(8, 64), 256, 0, stream>>>(out2g, WoT, p);
  } else {
    const size_t PH = 4096ull * 2048;
    for (int s = 0; s < 2; ++s) {
      k_attn<<<dim3(32, 16), 512, 0, stream>>>(q + (size_t)s * 4096 * 256, kk, attnB);
      uint16_t* Pa = out2g + (size_t)s * PH;
      uint16_t* Pb = out2g + (size_t)(1 - s) * PH;
      k_pv<<<dim3(256), 512, 0, stream>>>(attnB, vT, Pa, Pb, nullptr, 1);
      k_sum<<<dim3((int)(PH / 8 / 256)), 256, 0, stream>>>(
          Pa, Pb, gate + (size_t)s * PH, (int)(PH / 8));
      EpiParams p{};
      p.bias = b_out;
      p.x = x + (size_t)s * 4096 * 1024;
      p.o32 = out + (size_t)s * 4096 * 1024;
      k_final<<<dim3(8, 32), 256, 0, stream>>>(Pa, WoT, p);
    }
  }
}

// Round 10
// 605.545 us; speedup vs baseline: 1.0134x; 1.0134x over previous
//
#include <hip/hip_runtime.h>
#include <stdint.h>

// ---------------------------------------------------------------------------
// GAU forward on MI355X (gfx950), bf16 MFMA everywhere.
//   hid|qk = silu(x@[Wh|Wqk]+b) -> vT [2048][8192], gate [8192][2048],
//                                  q,k bf16 [8192][256] (cols 200..255 zero)
//   attn = relu(q@kT / 32)^2    bf16 (full [8192][8192] if ws allows)
//   out2 = (attn@v) * gate      bf16 [8192][2048]
//   y    = (out2@Wo + bo) * x   fp32 [8192][1024]
//
// R17 = R16 resubmitted with one defensive change: the ET loop is pinned
// #pragma unroll 1 (guards against a full-unroll compile blowup — a compile
// timeout also presents as "container failed twice"). Audit found no
// hang/deadlock path in the R16 schedule (uniform barriers, R9-equivalent
// ring/vmcnt invariant, bounds-checked k_prep). Decision rule: a third
// failure on this source = kernel-caused -> revert engine to R9 ET form.
//
// R16: (a) ENGINE256 = T3 per-phase interleave (m201-class): per BK=32 tile,
// TWO phases each {sub-tile ds_reads issued BEFORE a barrier; 2 stage
// gloads; barrier; 16-MFMA cluster AFTER it; barrier}, vmcnt(8) once per
// tile (counted, never drained — R9's proven ring-4 invariant). m196 A/B
// isolated this interleave as +28-41%. (b) prep fused into one k_prep.
// ---------------------------------------------------------------------------

typedef __bf16 bf16x8 __attribute__((ext_vector_type(8)));
typedef float f32x4 __attribute__((ext_vector_type(4)));

__device__ __forceinline__ uint16_t f2bf(float f) {
  uint32_t u = __builtin_bit_cast(uint32_t, f);
  u += 0x7fffu + ((u >> 16) & 1u);   // RNE; inputs are finite
  return (uint16_t)(u >> 16);
}
__device__ __forceinline__ float silu_f(float s) {
  return s / (1.f + __expf(-s));
}

__device__ __forceinline__ void gload16(const void* g, void* l) {
  __builtin_amdgcn_global_load_lds(
      (__attribute__((address_space(1))) void*)const_cast<void*>(g),
      (__attribute__((address_space(3))) void*)l, 16, 0, 0);
}

// ---------------- fused prep: cast + 3 transposes, one dispatch ----------------
// blocks [0,8192): xb cast; [8192,12288): WhT; [12288,12544): WqkT;
// [12544,14592): WoT. Transpose blocks: dim (32,8) emulated from 256 thr.

__device__ __forceinline__ void transpose_body(
    const float* __restrict__ in, uint16_t* __restrict__ out,
    int R, int C, int Cp, int bx, int by, int tx, int ty) {
  __shared__ float tile[32][33];
  int cb = bx * 32;
  int rb = by * 32;
#pragma unroll
  for (int i = 0; i < 4; ++i) {
    int r = rb + ty + i * 8;
    int c = cb + tx;
    tile[ty + i * 8][tx] = (c < C) ? in[(size_t)r * C + c] : 0.f;
  }
  __syncthreads();
#pragma unroll
  for (int i = 0; i < 4; ++i) {
    int c = cb + ty + i * 8;
    if (c < Cp) out[(size_t)c * R + rb + tx] = f2bf(tile[tx][ty + i * 8]);
  }
}

__global__ __launch_bounds__(256) void k_prep(
    const float* __restrict__ x, uint16_t* __restrict__ xb,
    const float* __restrict__ Wh, uint16_t* __restrict__ WhT,
    const float* __restrict__ Wqk, uint16_t* __restrict__ WqkT,
    const float* __restrict__ Wo, uint16_t* __restrict__ WoT) {
  const int id = blockIdx.x;
  const int tid = threadIdx.x;
  const int tx = tid & 31, ty = tid >> 5;
  if (id < 8192) {
    int i = id * 256 + tid;
    float4 f = ((const float4*)x)[i];
    ushort4 o;
    o.x = f2bf(f.x); o.y = f2bf(f.y); o.z = f2bf(f.z); o.w = f2bf(f.w);
    ((ushort4*)xb)[i] = o;
  } else if (id < 12288) {
    int l = id - 8192;                       // 128 x 32
    transpose_body(Wh, WhT, 1024, 4096, 4096, l & 127, l >> 7, tx, ty);
  } else if (id < 12544) {
    int l = id - 12288;                      // 8 x 32
    transpose_body(Wqk, WqkT, 1024, 200, 256, l & 7, l >> 3, tx, ty);
  } else {
    int l = id - 12544;                      // 32 x 64
    transpose_body(Wo, WoT, 2048, 1024, 1024, l & 31, l >> 5, tx, ty);
  }
}

// k_sum: P0 = (P0 + P1) * gate, elementwise bf16x8, in-place (striped path).
__global__ void k_sum(uint16_t* __restrict__ P0, const uint16_t* __restrict__ P1,
                      const uint16_t* __restrict__ g, int n8) {
  int i = blockIdx.x * blockDim.x + threadIdx.x;
  if (i < n8) {
    bf16x8 a = ((const bf16x8*)P0)[i];
    bf16x8 b = ((const bf16x8*)P1)[i];
    bf16x8 gg = ((const bf16x8*)g)[i];
    bf16x8 o;
#pragma unroll
    for (int e = 0; e < 8; ++e)
      o[e] = (__bf16)(((float)a[e] + (float)b[e]) * (float)gg[e]);
    ((bf16x8*)P0)[i] = o;
  }
}

// ---------------- params ----------------

struct EpiParams {
  const float* bias;
  const float* bias2;
  const float* g0;
  const float* b0;
  const float* g1;
  const float* b1;
  const uint16_t* gate;
  const float* x;
  uint16_t* o16a;
  uint16_t* o16b;
  uint16_t* oq;
  uint16_t* ok;
  float* o32;
};

// ---------------------------------------------------------------------------
// 256x256 8-wave T3 engine. Ring-4 slots of 32 KB (A 16K | B 16K),
// SH = uint16_t[65536]. Per tile t (slot t&3, stage slot (t+3)&3), 2 phases:
//   P0: read B[0-3]+A[0-3]; 2 gloads (A half of t+3); bar; MFMA acc[0-3][*];
//       bar
//   P1: read A[4-7]; 2 gloads (B half); bar; MFMA acc[4-7][*]; vmcnt(8); bar
// Residency: vmcnt(8) at end of t retires through tile t-2's stages = tile
// t+1's data (t+1 staged during t-2). Identical invariant to R9 (proven).
// B-frags held in regs across P0->P1.
// ---------------------------------------------------------------------------
#define ET(T_)                                                                 \
  do {                                                                         \
    const uint16_t* rb_ = SH + ((T_) & 3) * 16384;                             \
    uint16_t* sd_ = SH + (((T_) + 3) & 3) * 16384 + wave * 512;                \
    const int kp_ = (((T_) + 3) & (NT - 1)) * 32;                              \
    bf16x8 a_[4], b_[4];                                                       \
    _Pragma("unroll") for (int j_ = 0; j_ < 4; ++j_)                           \
        b_[j_] = *(const bf16x8*)(rb_ + rdB + j_ * 512);                       \
    _Pragma("unroll") for (int i_ = 0; i_ < 4; ++i_)                           \
        a_[i_] = *(const bf16x8*)(rb_ + rdA + i_ * 512);                       \
    gload16(gA0 + kp_, sd_);                                                   \
    gload16(gA1 + kp_, sd_ + 4096);                                            \
    __builtin_amdgcn_sched_barrier(0);                                         \
    __builtin_amdgcn_s_barrier();                                              \
    __builtin_amdgcn_sched_barrier(0);                                         \
    __builtin_amdgcn_s_setprio(1);                                             \
    _Pragma("unroll") for (int i_ = 0; i_ < 4; ++i_)                           \
      _Pragma("unroll") for (int j_ = 0; j_ < 4; ++j_)                         \
          acc[i_][j_] = __builtin_amdgcn_mfma_f32_16x16x32_bf16(               \
              a_[i_], b_[j_], acc[i_][j_], 0, 0, 0);                           \
    __builtin_amdgcn_s_setprio(0);                                             \
    __builtin_amdgcn_sched_barrier(0);                                         \
    __builtin_amdgcn_s_barrier();                                              \
    __builtin_amdgcn_sched_barrier(0);                                         \
    _Pragma("unroll") for (int i_ = 0; i_ < 4; ++i_)                           \
        a_[i_] = *(const bf16x8*)(rb_ + rdA + (4 + i_) * 512);                 \
    gload16(gB0 + kp_, sd_ + 8192);                                            \
    gload16(gB1 + kp_, sd_ + 12288);                                           \
    __builtin_amdgcn_sched_barrier(0);                                         \
    __builtin_amdgcn_s_barrier();                                              \
    __builtin_amdgcn_sched_barrier(0);                                         \
    __builtin_amdgcn_s_setprio(1);                                             \
    _Pragma("unroll") for (int i_ = 0; i_ < 4; ++i_)                           \
      _Pragma("unroll") for (int j_ = 0; j_ < 4; ++j_)                         \
          acc[4 + i_][j_] = __builtin_amdgcn_mfma_f32_16x16x32_bf16(           \
              a_[i_], b_[j_], acc[4 + i_][j_], 0, 0, 0);                       \
    __builtin_amdgcn_s_setprio(0);                                             \
    asm volatile("s_waitcnt vmcnt(8)" ::: "memory");                           \
    __builtin_amdgcn_sched_barrier(0);                                         \
    __builtin_amdgcn_s_barrier();                                              \
    __builtin_amdgcn_sched_barrier(0);                                         \
  } while (0)

#define ENGINE256()                                                            \
  do {                                                                         \
    _Pragma("unroll") for (int s_ = 0; s_ < 3; ++s_) {                         \
      uint16_t* d_ = SH + s_ * 16384 + wave * 512;                             \
      gload16(gA0 + s_ * 32, d_);                                              \
      gload16(gA1 + s_ * 32, d_ + 4096);                                       \
      gload16(gB0 + s_ * 32, d_ + 8192);                                       \
      gload16(gB1 + s_ * 32, d_ + 12288);                                      \
    }                                                                          \
    asm volatile("s_waitcnt vmcnt(8)" ::: "memory");                           \
    __builtin_amdgcn_sched_barrier(0);                                         \
    __builtin_amdgcn_s_barrier();                                              \
    __builtin_amdgcn_sched_barrier(0);                                         \
    _Pragma("unroll 1") for (int t_ = 0; t_ < NT; ++t_) ET(t_);                \
    asm volatile("s_waitcnt vmcnt(0)" ::: "memory");                           \
    __builtin_amdgcn_sched_barrier(0);                                         \
    __syncthreads();                                                           \
  } while (0)

// 128x128 4-wave ring-4 engine (k_final only; proven R9 structure).
#define TILE128(T_, B_, BS_)                                                   \
  do {                                                                         \
    const uint16_t* base_ = SH + (B_) * 8192;                                  \
    const int kp_ = (((T_) + 3) & (NT - 1)) * 32;                              \
    uint16_t* sd_ = SH + (BS_) * 8192 + wave * 512;                            \
    gload16(gA0 + kp_, sd_);                                                   \
    gload16(gA1 + kp_, sd_ + 2048);                                            \
    gload16(gB0 + kp_, sd_ + 4096);                                            \
    gload16(gB1 + kp_, sd_ + 6144);                                            \
    bf16x8 a_[4], b_[4];                                                       \
    _Pragma("unroll") for (int j_ = 0; j_ < 4; ++j_)                           \
        b_[j_] = *(const bf16x8*)(base_ + rdB + j_ * 512);                     \
    _Pragma("unroll") for (int i_ = 0; i_ < 4; ++i_)                           \
        a_[i_] = *(const bf16x8*)(base_ + rdA + i_ * 512);                     \
    __builtin_amdgcn_s_setprio(1);                                             \
    _Pragma("unroll") for (int i_ = 0; i_ < 4; ++i_)                           \
      _Pragma("unroll") for (int j_ = 0; j_ < 4; ++j_)                         \
          acc[i_][j_] = __builtin_amdgcn_mfma_f32_16x16x32_bf16(               \
              a_[i_], b_[j_], acc[i_][j_], 0, 0, 0);                           \
    __builtin_amdgcn_s_setprio(0);                                             \
    asm volatile("s_waitcnt vmcnt(8)" ::: "memory");                           \
    __builtin_amdgcn_sched_barrier(0);                                         \
    __builtin_amdgcn_s_barrier();                                              \
    __builtin_amdgcn_sched_barrier(0);                                         \
  } while (0)

#define RING_LOOP128()                                                         \
  do {                                                                         \
    _Pragma("unroll") for (int s_ = 0; s_ < 3; ++s_) {                         \
      uint16_t* d_ = SH + s_ * 8192 + wave * 512;                              \
      gload16(gA0 + s_ * 32, d_);                                              \
      gload16(gA1 + s_ * 32, d_ + 2048);                                       \
      gload16(gB0 + s_ * 32, d_ + 4096);                                       \
      gload16(gB1 + s_ * 32, d_ + 6144);                                       \
    }                                                                          \
    asm volatile("s_waitcnt vmcnt(8)" ::: "memory");                           \
    __builtin_amdgcn_sched_barrier(0);                                         \
    __builtin_amdgcn_s_barrier();                                              \
    __builtin_amdgcn_sched_barrier(0);                                         \
    for (int t0_ = 0; t0_ < NT; t0_ += 4) {                                    \
      TILE128(t0_ + 0, 0, 3);                                                  \
      TILE128(t0_ + 1, 1, 0);                                                  \
      TILE128(t0_ + 2, 2, 1);                                                  \
      TILE128(t0_ + 3, 3, 2);                                                  \
    }                                                                          \
    asm volatile("s_waitcnt vmcnt(0)" ::: "memory");                           \
    __builtin_amdgcn_sched_barrier(0);                                         \
    __syncthreads();                                                           \
  } while (0)

// ---------------------------------------------------------------------------
// k_hidqk: C = xb[8192,1024] @ [WhT;WqkT][4352,1024]^T, 256x256, 8 waves.
// ---------------------------------------------------------------------------
__global__ __launch_bounds__(512, 2) void k_hidqk(
    const uint16_t* __restrict__ A, const uint16_t* __restrict__ Bt, EpiParams p) {
  __shared__ __align__(16) uint16_t SH[65536];   // 128 KB ring

  const int tid = threadIdx.x;
  const int lane = tid & 63;
  const int wave = tid >> 6;
  const int wrM = (wave >> 2) * 128;
  const int wcN = (wave & 3) * 64;
  const int m0 = blockIdx.y * 256;
  const int n0 = blockIdx.x * 256;
  const int lda = 1024, ldb = 1024;
  const int NT = 32;   // K=1024

  f32x4 acc[8][4] = {};

  const int fr = lane & 15;
  const int rg = lane >> 4;
  const int swz = (rg ^ ((fr >> 1) & 3)) * 8;
  const int rdA = (wrM + fr) * 32 + swz;
  const int rdB = 8192 + (wcN + fr) * 32 + swz;

  const int srow = lane >> 2;
  const int sk = ((lane & 3) ^ ((lane >> 3) & 3)) * 8;
  const uint16_t* gA0 = A + (size_t)(m0 + wave * 16 + srow) * lda + sk;
  const uint16_t* gA1 = gA0 + (size_t)128 * lda;
  const uint16_t* gB0 = Bt + (size_t)(n0 + wave * 16 + srow) * ldb + sk;
  const uint16_t* gB1 = gB0 + (size_t)128 * ldb;

  ENGINE256();

  // C/D layout: col = lane&15, row = rg*4 + reg   [m89-verified]
  if (n0 < 2048) {
    // vT transposed store. Per j: arena [16 n][128 m + 8 pad] stride 136.
    uint16_t* ar = SH + wave * 2304;
#pragma unroll
    for (int j = 0; j < 4; ++j) {
      const float bc = p.bias[n0 + wcN + j * 16 + fr];
#pragma unroll
      for (int i = 0; i < 8; ++i)
#pragma unroll
        for (int r = 0; r < 4; ++r)
          ar[fr * 136 + i * 16 + rg * 4 + r] = f2bf(silu_f(acc[i][j][r] + bc));
      const int mc = (lane & 15) * 8;
#pragma unroll
      for (int it = 0; it < 4; ++it) {
        const int nrow = it * 4 + (lane >> 4);
        bf16x8 v = *(const bf16x8*)(ar + nrow * 136 + mc);
        *(bf16x8*)(p.o16a + (size_t)(n0 + wcN + j * 16 + nrow) * 8192 + m0 + wrM + mc) = v;
      }
    }
  } else if (n0 < 4096) {
    // gate. Per i: arena [16 m][64 n + pad] stride 72.
    uint16_t* ar = SH + wave * 2048;
    const int lrow = lane >> 3;
    const int nc = (lane & 7) * 8;
    float bc[4];
#pragma unroll
    for (int j = 0; j < 4; ++j) bc[j] = p.bias[n0 + wcN + j * 16 + fr];
#pragma unroll
    for (int i = 0; i < 8; ++i) {
#pragma unroll
      for (int j = 0; j < 4; ++j)
#pragma unroll
        for (int r = 0; r < 4; ++r)
          ar[(rg * 4 + r) * 72 + j * 16 + fr] = f2bf(silu_f(acc[i][j][r] + bc[j]));
#pragma unroll
      for (int rr = 0; rr < 2; ++rr) {
        bf16x8 v = *(const bf16x8*)(ar + (rr * 8 + lrow) * 72 + nc);
        *(bf16x8*)(p.o16b + (size_t)(m0 + wrM + i * 16 + rr * 8 + lrow) * 2048 + (n0 - 2048) + wcN + nc) = v;
      }
    }
  } else {
    // q,k: stride 256, cols 200..255 forced zero. n0==4096 -> qc = wcN+j*16+fr.
#pragma unroll
    for (int i = 0; i < 8; ++i) {
#pragma unroll
      for (int j = 0; j < 4; ++j) {
        const int row = m0 + wrM + i * 16 + rg * 4;
        const int qc = wcN + j * 16 + fr;   // 0..255
#pragma unroll
        for (int r = 0; r < 4; ++r) {
          float qv = 0.f, kv = 0.f;
          if (qc < 200) {
            float s = silu_f(acc[i][j][r] + p.bias2[qc]);
            qv = s * p.g0[qc] + p.b0[qc];
            kv = s * p.g1[qc] + p.b1[qc];
          }
          p.oq[(size_t)(row + r) * 256 + qc] = f2bf(qv);
          p.ok[(size_t)(row + r) * 256 + qc] = f2bf(kv);
        }
      }
    }
  }
}

// ---------------------------------------------------------------------------
// k_attn: attn = relu(q@kT/32)^2, K=256 (padded), 256x256 tile, 8 waves.
// ---------------------------------------------------------------------------
__global__ __launch_bounds__(512, 2) void k_attn(
    const uint16_t* __restrict__ Q,
    const uint16_t* __restrict__ Kt,
    uint16_t* __restrict__ attn) {
  __shared__ __align__(16) uint16_t SH[65536];

  const int tid = threadIdx.x;
  const int lane = tid & 63;
  const int wave = tid >> 6;
  const int wrM = (wave >> 2) * 128;
  const int wcN = (wave & 3) * 64;
  const int m0 = blockIdx.y * 256;
  const int n0 = blockIdx.x * 256;
  const int lda = 256, ldb = 256;
  const int NT = 8;   // K=256

  f32x4 acc[8][4] = {};

  const int fr = lane & 15;
  const int rg = lane >> 4;
  const int swz = (rg ^ ((fr >> 1) & 3)) * 8;
  const int rdA = (wrM + fr) * 32 + swz;
  const int rdB = 8192 + (wcN + fr) * 32 + swz;

  const int srow = lane >> 2;
  const int sk = ((lane & 3) ^ ((lane >> 3) & 3)) * 8;
  const uint16_t* gA0 = Q + (size_t)(m0 + wave * 16 + srow) * lda + sk;
  const uint16_t* gA1 = gA0 + (size_t)128 * lda;
  const uint16_t* gB0 = Kt + (size_t)(n0 + wave * 16 + srow) * ldb + sk;
  const uint16_t* gB1 = gB0 + (size_t)128 * ldb;

  ENGINE256();

  uint16_t* ar = SH + wave * 2048;
  const int row = lane >> 2;
  const int c0 = (lane & 3) * 16;
#pragma unroll
  for (int i = 0; i < 8; ++i) {
#pragma unroll
    for (int j = 0; j < 4; ++j)
#pragma unroll
      for (int r = 0; r < 4; ++r) {
        float s = fmaxf(acc[i][j][r] * 0.03125f, 0.f);
        ar[(rg * 4 + r) * 72 + j * 16 + fr] = f2bf(s * s);
      }
    bf16x8 v0 = *(const bf16x8*)(ar + row * 72 + c0);
    bf16x8 v1 = *(const bf16x8*)(ar + row * 72 + c0 + 8);
    uint16_t* dst = attn + (size_t)(m0 + wrM + i * 16 + row) * 8192 + (n0 + wcN + c0);
    *(bf16x8*)(dst) = v0;
    *(bf16x8*)(dst + 8) = v1;
  }
}

// ---------------------------------------------------------------------------
// k_pv: out2 = (attn@v)[*gate]. 256x256 tile, 8 waves, T3 engine (BK=32
// ring-4). split=0 (fullM): grid 256, K=8192, gated store. split=1:
// kv-halves, raw partials.
// ---------------------------------------------------------------------------
__global__ __launch_bounds__(512, 2) void k_pv(
    const uint16_t* __restrict__ A,
    const uint16_t* __restrict__ Bt,
    uint16_t* __restrict__ P0,
    uint16_t* __restrict__ P1,
    const uint16_t* __restrict__ gate,
    int split) {
  __shared__ __align__(16) uint16_t SH[65536];

  const int id = blockIdx.x;
  int bx, by, kv0, NT;
  uint16_t* dst;
  if (split) {
    bx = id & 7;
    by = id >> 4;
    kv0 = ((id >> 3) & 1) * 4096;
    NT = 128;
    dst = ((id >> 3) & 1) ? P1 : P0;
  } else {
    bx = (id >> 3) & 7;
    by = (id & 7) + 8 * (id >> 6);
    kv0 = 0;
    NT = 256;
    dst = P0;
  }
  const int m0 = by * 256;
  const int n0 = bx * 256;

  const int tid = threadIdx.x;
  const int lane = tid & 63;
  const int wave = tid >> 6;
  const int wrM = (wave >> 2) * 128;
  const int wcN = (wave & 3) * 64;

  const int fr = lane & 15;
  const int rg = lane >> 4;
  const int swz = (rg ^ ((fr >> 1) & 3)) * 8;
  const int rdA = (wrM + fr) * 32 + swz;
  const int rdB = 8192 + (wcN + fr) * 32 + swz;

  const int srow = lane >> 2;
  const int sk = ((lane & 3) ^ ((lane >> 3) & 3)) * 8;
  const uint16_t* gA0 = A + (size_t)(m0 + wave * 16 + srow) * 8192 + kv0 + sk;
  const uint16_t* gA1 = gA0 + (size_t)128 * 8192;
  const uint16_t* gB0 = Bt + (size_t)(n0 + wave * 16 + srow) * 8192 + kv0 + sk;
  const uint16_t* gB1 = gB0 + (size_t)128 * 8192;

  f32x4 acc[8][4] = {};
  ENGINE256();

  // epilogue: per-wave [16][72] arena bounce, 16B stores (gated if fullM)
  uint16_t* ar = SH + wave * 2048;
  const int lrow = lane >> 3;
  const int nc = (lane & 7) * 8;
#pragma unroll
  for (int i = 0; i < 8; ++i) {
#pragma unroll
    for (int j = 0; j < 4; ++j)
#pragma unroll
      for (int r = 0; r < 4; ++r)
        ar[(rg * 4 + r) * 72 + j * 16 + fr] = f2bf(acc[i][j][r]);
#pragma unroll
    for (int rr = 0; rr < 2; ++rr) {
      const size_t base = (size_t)(m0 + wrM + i * 16 + rr * 8 + lrow) * 2048 + n0 + wcN + nc;
      bf16x8 v = *(const bf16x8*)(ar + (rr * 8 + lrow) * 72 + nc);
      if (gate) {
        bf16x8 g = *(const bf16x8*)(gate + base);
        bf16x8 o;
#pragma unroll
        for (int e = 0; e < 8; ++e) o[e] = (__bf16)((float)v[e] * (float)g[e]);
        *(bf16x8*)(dst + base) = o;
      } else {
        *(bf16x8*)(dst + base) = v;
      }
    }
  }
}

// ---------------------------------------------------------------------------
// k_final: y = (out2g@WoT^T + bo) * x, fp32 out. 128x128, K=2048, ring-4.
// ---------------------------------------------------------------------------
__global__ __launch_bounds__(256, 2) void k_final(
    const uint16_t* __restrict__ A,
    const uint16_t* __restrict__ Bt, EpiParams p) {
  __shared__ __align__(16) uint16_t SH[32768];

  const int tid = threadIdx.x;
  const int lane = tid & 63;
  const int wave = tid >> 6;
  const int wr = (wave >> 1) * 64;
  const int wc = (wave & 1) * 64;
  const int m0 = blockIdx.y * 128;
  const int n0 = blockIdx.x * 128;
  const int lda = 2048, ldb = 2048;
  const int NT = 64;   // K=2048

  f32x4 acc[4][4] = {};

  const int fr = lane & 15;
  const int rg = lane >> 4;
  const int swz = (rg ^ ((fr >> 1) & 3)) * 8;
  const int rdA = (wr + fr) * 32 + swz;
  const int rdB = 4096 + (wc + fr) * 32 + swz;

  const int srow = lane >> 2;
  const int sk = ((lane & 3) ^ ((lane >> 3) & 3)) * 8;
  const uint16_t* gA0 = A + (size_t)(m0 + wave * 16 + srow) * lda + sk;
  const uint16_t* gA1 = gA0 + (size_t)64 * lda;
  const uint16_t* gB0 = Bt + (size_t)(n0 + wave * 16 + srow) * ldb + sk;
  const uint16_t* gB1 = gB0 + (size_t)64 * ldb;

  RING_LOOP128();

#pragma unroll
  for (int i = 0; i < 4; ++i) {
#pragma unroll
    for (int j = 0; j < 4; ++j) {
      const int row = m0 + wr + i * 16 + rg * 4;
      const int col = n0 + wc + j * 16 + fr;
      const float bc = p.bias[col];
#pragma unroll
      for (int r = 0; r < 4; ++r) {
        size_t idx = (size_t)(row + r) * 1024 + col;
        p.o32[idx] = (acc[i][j][r] + bc) * p.x[idx];
      }
    }
  }
}

// ---------------- launch ----------------

extern "C" void kernel_launch(void* const* d_in, const int* in_sizes, int n_in,
                              void* d_out, int out_size, void* d_ws, size_t ws_size,
                              hipStream_t stream) {
  const float* x        = (const float*)d_in[0];
  const float* W_hidden = (const float*)d_in[1];
  const float* b_hidden = (const float*)d_in[2];
  const float* W_qk     = (const float*)d_in[3];
  const float* b_qk     = (const float*)d_in[4];
  const float* gamma    = (const float*)d_in[5];
  const float* beta     = (const float*)d_in[6];
  const float* W_out    = (const float*)d_in[7];
  const float* b_out    = (const float*)d_in[8];
  float* out = (float*)d_out;

  const bool fullM = ws_size >= (236ull << 20);
  const size_t region0 = fullM ? (128ull << 20) : (64ull << 20);

  char* base = (char*)d_ws;
  uint16_t* xb    = (uint16_t*)(base);                         // 16 MB  [8192][1024]
  uint16_t* WhT   = (uint16_t*)(base + (16ull << 20));         //  8 MB  [4096][1024]
  uint16_t* WqkT  = (uint16_t*)(base + (24ull << 20));         // .5 MB  [256][1024]
  uint16_t* attnB = (uint16_t*)(base);                         // 64/128 MB
  char* tail = base + region0;
  uint16_t* WoT   = (uint16_t*)(tail);                         //  4 MB  [1024][2048]
  uint16_t* q     = (uint16_t*)(tail + (4ull << 20));          //  4 MB  [8192][256]
  uint16_t* kk    = (uint16_t*)(tail + (8ull << 20));          //  4 MB
  uint16_t* vT    = (uint16_t*)(tail + (12ull << 20));         // 32 MB  [2048][8192]
  uint16_t* gate  = (uint16_t*)(tail + (44ull << 20));         // 32 MB  [8192][2048]
  uint16_t* out2g = (uint16_t*)(tail + (76ull << 20));         // 32 MB  [8192][2048]
  (void)in_sizes; (void)n_in; (void)out_size;

  // fused prep: cast + 3 transposes (one dispatch)
  k_prep<<<dim3(14592), 256, 0, stream>>>(x, xb, W_hidden, WhT, W_qk, WqkT, W_out, WoT);

  // fused hid + qk   (N = 4096 + 256 = 4352; blocks x: 0..7 vT, 8..15 gate, 16 qk)
  {
    EpiParams p{};
    p.bias = b_hidden; p.bias2 = b_qk;
    p.g0 = gamma; p.b0 = beta; p.g1 = gamma + 200; p.b1 = beta + 200;
    p.o16a = vT; p.o16b = gate; p.oq = q; p.ok = kk;
    k_hidqk<<<dim3(17, 32), 512, 0, stream>>>(xb, WhT, p);
  }

  if (fullM) {
    k_attn<<<dim3(32, 32), 512, 0, stream>>>(q, kk, attnB);
    k_pv<<<dim3(256), 512, 0, stream>>>(attnB, vT, out2g, nullptr, gate, 0);
    EpiParams p{};
    p.bias = b_out; p.x = x; p.o32 = out;
    k_final<<<dim3(8, 64), 256, 0, stream>>>(out2g, WoT, p);
  } else {
    const size_t PH = 4096ull * 2048;
    for (int s = 0; s < 2; ++s) {
      k_attn<<<dim3(32, 16), 512, 0, stream>>>(q + (size_t)s * 4096 * 256, kk, attnB);
      uint16_t* Pa = out2g + (size_t)s * PH;
      uint16_t* Pb = out2g + (size_t)(1 - s) * PH;
      k_pv<<<dim3(256), 512, 0, stream>>>(attnB, vT, Pa, Pb, nullptr, 1);
      k_sum<<<dim3((int)(PH / 8 / 256)), 256, 0, stream>>>(
          Pa, Pb, gate + (size_t)s * PH, (int)(PH / 8));
      EpiParams p{};
      p.bias = b_out;
      p.x = x + (size_t)s * 4096 * 1024;
      p.o32 = out + (size_t)s * 4096 * 1024;
      k_final<<<dim3(8, 32), 256, 0, stream>>>(Pa, WoT, p);
    }
  }
}